// Round 1
// baseline (1535.880 us; speedup 1.0000x reference)
//
#include <hip/hip_runtime.h>
#include <hip/hip_bf16.h>

#define B_ 4
#define N_ 1024
#define D_ 1024
#define E_ 8
#define H_ 2730
#define H2_ 5460
#define CAP_ 256
#define NTOK 4096
#define NSLOT 8192
#define ACTP 2752   // H padded to multiple of 32

typedef __attribute__((ext_vector_type(8))) short short8;
typedef __attribute__((ext_vector_type(4))) float f32x4;

__device__ __forceinline__ unsigned short f2bf(float f) {
    __hip_bfloat16 h = __float2bfloat16(f);
    return *reinterpret_cast<unsigned short*>(&h);
}

// ---------------- gating: logits, softmax, top-2, should_route ----------------
__global__ __launch_bounds__(256) void k_gate(const float* __restrict__ x,
                                              const float* __restrict__ route,
                                              const float* __restrict__ gw,
                                              int* __restrict__ tokE,
                                              float* __restrict__ tokG,
                                              int* __restrict__ tokR) {
    const int wave = threadIdx.x >> 6, lane = threadIdx.x & 63;
    const int t = blockIdx.x * 4 + wave;   // token index = b*N + n
    float acc[E_];
#pragma unroll
    for (int e = 0; e < E_; ++e) acc[e] = 0.f;
    const float* xr = x + (size_t)t * D_;
    for (int d = lane; d < D_; d += 64) {
        float xv = xr[d];
        const float* g = gw + d * E_;
#pragma unroll
        for (int e = 0; e < E_; ++e) acc[e] = fmaf(xv, g[e], acc[e]);
    }
#pragma unroll
    for (int e = 0; e < E_; ++e) {
#pragma unroll
        for (int off = 32; off; off >>= 1) acc[e] += __shfl_xor(acc[e], off);
    }
    if (lane == 0) {
        float m = acc[0];
#pragma unroll
        for (int e = 1; e < E_; ++e) m = fmaxf(m, acc[e]);
        float p[E_]; float s = 0.f;
#pragma unroll
        for (int e = 0; e < E_; ++e) { p[e] = expf(acc[e] - m); s += p[e]; }
        // top-2 (ties -> lower index, matching jax.lax.top_k)
        int i0 = 0; float v0 = p[0];
#pragma unroll
        for (int e = 1; e < E_; ++e) if (p[e] > v0) { v0 = p[e]; i0 = e; }
        int i1 = (i0 == 0) ? 1 : 0; float v1 = p[i1];
#pragma unroll
        for (int e = 0; e < E_; ++e) if (e != i0 && p[e] > v1) { v1 = p[e]; i1 = e; }
        float p0 = v0 / s, p1 = v1 / s;
        float denom = fmaxf(p0 + p1, 1e-9f);
        float g0 = p0 / denom, g1 = p1 / denom;
        int r1 = route[NTOK + t] < (g1 / 0.2f);
        tokE[t] = i0; tokE[NTOK + t] = i1;
        tokG[t] = g0; tokG[NTOK + t] = g1;
        tokR[t] = r1;
    }
}

// ---------------- positions: per (b,e) exclusive cumsum + capacity ----------------
__global__ __launch_bounds__(256) void k_pos(const int* __restrict__ tokE,
                                             const float* __restrict__ tokG,
                                             const int* __restrict__ tokR,
                                             int* __restrict__ sot,   // slot_of_token [2][NTOK]
                                             int* __restrict__ tos) { // token_of_slot [NSLOT]
    const int e = blockIdx.x & 7, b = blockIdx.x >> 3;
    const int t = threadIdx.x;
    __shared__ int sc[256];
    const int base_bt = b * N_ + t * 4;
    int m0[4], m1[4];
    int c0 = 0, c1 = 0;
#pragma unroll
    for (int i = 0; i < 4; ++i) {
        int bt = base_bt + i;
        m0[i] = (tokE[bt] == e) ? 1 : 0;
        m1[i] = ((tokE[NTOK + bt] == e) && tokR[bt]) ? 1 : 0;
        c0 += m0[i]; c1 += m1[i];
    }
    int packed = c0 | (c1 << 16);
    sc[t] = packed;
    __syncthreads();
    for (int off = 1; off < 256; off <<= 1) {
        int v = (t >= off) ? sc[t - off] : 0;
        __syncthreads();
        sc[t] += v;
        __syncthreads();
    }
    int incl = sc[t];
    int total = sc[255];
    int excl = incl - packed;
    int base0 = excl & 0xffff;
    int base1 = excl >> 16;
    int kept0 = min(total & 0xffff, CAP_);
#pragma unroll
    for (int i = 0; i < 4; ++i) {
        int bt = base_bt + i;
        if (m0[i]) {
            int pos = base0++;   // raw cumsum consumes position regardless of keep
            if (pos < CAP_ && tokG[bt] > 0.f) {
                int s = ((e * B_ + b) << 8) + pos;
                sot[bt] = s;
                tos[s] = bt;
            }
        }
        if (m1[i]) {
            int pos = (base1++) + kept0;
            if (pos < CAP_ && tokG[NTOK + bt] > 0.f) {
                int s = ((e * B_ + b) << 8) + pos;
                sot[NTOK + bt] = s;
                tos[s] = bt;
            }
        }
    }
}

// ---------------- dispatch: gather x rows -> bf16 xe ----------------
__global__ __launch_bounds__(256) void k_disp(const float* __restrict__ x,
                                              const int* __restrict__ tos,
                                              unsigned short* __restrict__ xe) {
    const int s = blockIdx.x;
    const int bt = tos[s];
    const int t = threadIdx.x;
    ushort4 o;
    if (bt >= 0) {
        const float4 v = *reinterpret_cast<const float4*>(x + (size_t)bt * D_ + t * 4);
        o.x = f2bf(v.x); o.y = f2bf(v.y); o.z = f2bf(v.z); o.w = f2bf(v.w);
    } else {
        o.x = 0; o.y = 0; o.z = 0; o.w = 0;
    }
    *reinterpret_cast<ushort4*>(xe + (size_t)s * D_ + t * 4) = o;
}

// ---------------- GEMM1 + GEGLU: act = gelu(xe*W1g+b1g) * (xe*W1v+b1v) * mult ----------------
#define LDP 40  // padded LDS stride (elements)
__global__ __launch_bounds__(256) void k_ffn1(const unsigned short* __restrict__ xe,
                                              const float* __restrict__ w1,
                                              const float* __restrict__ b1,
                                              const float* __restrict__ mbias,
                                              unsigned short* __restrict__ act) {
    const int ct = blockIdx.x;   // 0..42 col tile (64 cols)
    const int rt = blockIdx.y;   // 0..7 row tile (128 rows)
    const int e  = blockIdx.z;
    const int jv = ct * 64;
    __shared__ unsigned short As[128 * LDP];
    __shared__ unsigned short Bv[64 * LDP];
    __shared__ unsigned short Bg[64 * LDP];
    const int tid = threadIdx.x;
    const int lane = tid & 63, wv = tid >> 6;
    const int wr = wv >> 1, wc = wv & 1;

    f32x4 accv[4][2], accg[4][2];
#pragma unroll
    for (int i = 0; i < 4; ++i)
#pragma unroll
        for (int j = 0; j < 2; ++j) { accv[i][j] = (f32x4)(0.f); accg[i][j] = (f32x4)(0.f); }

    // A staging map: pair of threads per row
    const int ar = tid >> 1, akh = (tid & 1) * 16;
    const unsigned short* aptr = xe + ((size_t)(e * 1024 + rt * 128 + ar)) * D_ + akh;
    // B staging map: thread -> (n, k-octet)
    const int bn = tid & 63, bq = tid >> 6;
    const bool fok = (jv + bn) < H_;
    const float* w1e = w1 + (size_t)e * D_ * H2_;
    const float* bvp = w1e + (size_t)(bq * 8) * H2_ + jv + bn;
    const float* bgp = bvp + H_;

    const int fr_row = (lane & 15) * LDP + (lane >> 4) * 8;

    for (int kk = 0; kk < 32; ++kk) {
        const int k0 = kk * 32;
        uint4 a0 = *reinterpret_cast<const uint4*>(aptr + k0);
        uint4 a1 = *reinterpret_cast<const uint4*>(aptr + k0 + 8);
        unsigned short vv[8], gg[8];
#pragma unroll
        for (int i = 0; i < 8; ++i) {
            float fv = fok ? bvp[(size_t)(k0 + i) * H2_] : 0.f;
            float fg = fok ? bgp[(size_t)(k0 + i) * H2_] : 0.f;
            vv[i] = f2bf(fv); gg[i] = f2bf(fg);
        }
        *reinterpret_cast<uint4*>(&As[ar * LDP + akh])     = a0;
        *reinterpret_cast<uint4*>(&As[ar * LDP + akh + 8]) = a1;
        uint4 pv, pg;
        pv.x = (unsigned)vv[0] | ((unsigned)vv[1] << 16);
        pv.y = (unsigned)vv[2] | ((unsigned)vv[3] << 16);
        pv.z = (unsigned)vv[4] | ((unsigned)vv[5] << 16);
        pv.w = (unsigned)vv[6] | ((unsigned)vv[7] << 16);
        pg.x = (unsigned)gg[0] | ((unsigned)gg[1] << 16);
        pg.y = (unsigned)gg[2] | ((unsigned)gg[3] << 16);
        pg.z = (unsigned)gg[4] | ((unsigned)gg[5] << 16);
        pg.w = (unsigned)gg[6] | ((unsigned)gg[7] << 16);
        *reinterpret_cast<uint4*>(&Bv[bn * LDP + bq * 8]) = pv;
        *reinterpret_cast<uint4*>(&Bg[bn * LDP + bq * 8]) = pg;
        __syncthreads();

        short8 bfv[2], bfg[2];
#pragma unroll
        for (int nc = 0; nc < 2; ++nc) {
            int nb = (wc * 32 + nc * 16) * LDP;
            bfv[nc] = *reinterpret_cast<const short8*>(&Bv[nb + fr_row]);
            bfg[nc] = *reinterpret_cast<const short8*>(&Bg[nb + fr_row]);
        }
#pragma unroll
        for (int mr = 0; mr < 4; ++mr) {
            short8 af = *reinterpret_cast<const short8*>(&As[(wr * 64 + mr * 16) * LDP + fr_row]);
#pragma unroll
            for (int nc = 0; nc < 2; ++nc) {
                accv[mr][nc] = __builtin_amdgcn_mfma_f32_16x16x32_bf16(af, bfv[nc], accv[mr][nc], 0, 0, 0);
                accg[mr][nc] = __builtin_amdgcn_mfma_f32_16x16x32_bf16(af, bfg[nc], accg[mr][nc], 0, 0, 0);
            }
        }
        __syncthreads();
    }

    // epilogue: bias + exact GELU + mult_bias, store bf16 (zero the K-pad columns)
    const float* b1e = b1 + (size_t)e * H2_;
    const float* mbe = mbias + (size_t)e * H_;
    const int col = lane & 15, rowq = (lane >> 4) * 4;
    const int Rbase = rt * 128 + wr * 64;
#pragma unroll
    for (int mr = 0; mr < 4; ++mr) {
#pragma unroll
        for (int nc = 0; nc < 2; ++nc) {
            int f = jv + wc * 32 + nc * 16 + col;
#pragma unroll
            for (int j = 0; j < 4; ++j) {
                int R = Rbase + mr * 16 + rowq + j;
                size_t o = ((size_t)(e * 1024 + R)) * ACTP + f;
                if (f < H_) {
                    float val = accv[mr][nc][j] + b1e[f];
                    float gt  = accg[mr][nc][j] + b1e[H_ + f];
                    float a = 0.5f * gt * (1.f + erff(gt * 0.70710678118654752f)) * val * mbe[f];
                    act[o] = f2bf(a);
                } else {
                    act[o] = 0;   // pad region [H_, ACTP)
                }
            }
        }
    }
}

// ---------------- GEMM2: out_e = act * W2 + b2 ----------------
__global__ __launch_bounds__(256) void k_ffn2(const unsigned short* __restrict__ act,
                                              const float* __restrict__ w2,
                                              const float* __restrict__ b2,
                                              float* __restrict__ oute) {
    const int ct = blockIdx.x;   // 0..7 col tile (128 cols of D)
    const int rt = blockIdx.y;   // 0..7 row tile
    const int e  = blockIdx.z;
    __shared__ unsigned short As[128 * LDP];
    __shared__ unsigned short Bs[128 * LDP];
    const int tid = threadIdx.x;
    const int lane = tid & 63, wv = tid >> 6;
    const int wr = wv >> 1, wc = wv & 1;

    f32x4 acc[4][4];
#pragma unroll
    for (int i = 0; i < 4; ++i)
#pragma unroll
        for (int j = 0; j < 4; ++j) acc[i][j] = (f32x4)(0.f);

    const int ar = tid >> 1, akh = (tid & 1) * 16;
    const unsigned short* aptr = act + ((size_t)(e * 1024 + rt * 128 + ar)) * ACTP + akh;
    const int bn = tid & 127, bq = tid >> 7;   // bq 0/1 -> k sedectet
    const float* w2e = w2 + (size_t)e * H_ * D_;
    const float* bptr = w2e + (size_t)(bq * 16) * D_ + ct * 128 + bn;

    const int fr_row = (lane & 15) * LDP + (lane >> 4) * 8;

    for (int kk = 0; kk < 86; ++kk) {
        const int k0 = kk * 32;
        uint4 a0 = *reinterpret_cast<const uint4*>(aptr + k0);
        uint4 a1 = *reinterpret_cast<const uint4*>(aptr + k0 + 8);
        unsigned short bb[16];
#pragma unroll
        for (int i = 0; i < 16; ++i) {
            int k = k0 + bq * 16 + i;
            float f = (k < H_) ? bptr[(size_t)(k0 + i) * D_] : 0.f;
            bb[i] = f2bf(f);
        }
        *reinterpret_cast<uint4*>(&As[ar * LDP + akh])     = a0;
        *reinterpret_cast<uint4*>(&As[ar * LDP + akh + 8]) = a1;
        uint4 p0, p1;
        p0.x = (unsigned)bb[0]  | ((unsigned)bb[1]  << 16);
        p0.y = (unsigned)bb[2]  | ((unsigned)bb[3]  << 16);
        p0.z = (unsigned)bb[4]  | ((unsigned)bb[5]  << 16);
        p0.w = (unsigned)bb[6]  | ((unsigned)bb[7]  << 16);
        p1.x = (unsigned)bb[8]  | ((unsigned)bb[9]  << 16);
        p1.y = (unsigned)bb[10] | ((unsigned)bb[11] << 16);
        p1.z = (unsigned)bb[12] | ((unsigned)bb[13] << 16);
        p1.w = (unsigned)bb[14] | ((unsigned)bb[15] << 16);
        *reinterpret_cast<uint4*>(&Bs[bn * LDP + bq * 16])     = p0;
        *reinterpret_cast<uint4*>(&Bs[bn * LDP + bq * 16 + 8]) = p1;
        __syncthreads();

        short8 af[4], bf[4];
#pragma unroll
        for (int mr = 0; mr < 4; ++mr)
            af[mr] = *reinterpret_cast<const short8*>(&As[(wr * 64 + mr * 16) * LDP + fr_row]);
#pragma unroll
        for (int nc = 0; nc < 4; ++nc)
            bf[nc] = *reinterpret_cast<const short8*>(&Bs[(wc * 64 + nc * 16) * LDP + fr_row]);
#pragma unroll
        for (int mr = 0; mr < 4; ++mr)
#pragma unroll
            for (int nc = 0; nc < 4; ++nc)
                acc[mr][nc] = __builtin_amdgcn_mfma_f32_16x16x32_bf16(af[mr], bf[nc], acc[mr][nc], 0, 0, 0);
        __syncthreads();
    }

    const float* b2e = b2 + (size_t)e * D_;
    const int col = lane & 15, rowq = (lane >> 4) * 4;
#pragma unroll
    for (int mr = 0; mr < 4; ++mr) {
#pragma unroll
        for (int nc = 0; nc < 4; ++nc) {
            int d = ct * 128 + wc * 64 + nc * 16 + col;
#pragma unroll
            for (int j = 0; j < 4; ++j) {
                int R = rt * 128 + wr * 64 + mr * 16 + rowq + j;
                oute[((size_t)(e * 1024 + R)) * D_ + d] = acc[mr][nc][j] + b2e[d];
            }
        }
    }
}

// ---------------- combine ----------------
__global__ __launch_bounds__(256) void k_comb(const float* __restrict__ oute,
                                              const int* __restrict__ sot,
                                              const float* __restrict__ tokG,
                                              float* __restrict__ out) {
    const int bt = blockIdx.x;
    const int t = threadIdx.x;
    const int s0 = sot[bt], s1 = sot[NTOK + bt];
    const float g0 = tokG[bt], g1 = tokG[NTOK + bt];
    float r0 = 0.f, r1 = 0.f, r2 = 0.f, r3 = 0.f;
    if (s0 >= 0) {
        const float4 v = *reinterpret_cast<const float4*>(oute + (size_t)s0 * D_ + t * 4);
        r0 += g0 * v.x; r1 += g0 * v.y; r2 += g0 * v.z; r3 += g0 * v.w;
    }
    if (s1 >= 0) {
        const float4 v = *reinterpret_cast<const float4*>(oute + (size_t)s1 * D_ + t * 4);
        r0 += g1 * v.x; r1 += g1 * v.y; r2 += g1 * v.z; r3 += g1 * v.w;
    }
    float4 o; o.x = r0; o.y = r1; o.z = r2; o.w = r3;
    *reinterpret_cast<float4*>(out + (size_t)bt * D_ + t * 4) = o;
}

extern "C" void kernel_launch(void* const* d_in, const int* in_sizes, int n_in,
                              void* d_out, int out_size, void* d_ws, size_t ws_size,
                              hipStream_t stream) {
    const float* x     = (const float*)d_in[0];
    const float* route = (const float*)d_in[1];
    const float* gw    = (const float*)d_in[2];
    const float* w1    = (const float*)d_in[3];
    const float* b1    = (const float*)d_in[4];
    const float* mb    = (const float*)d_in[5];
    const float* w2    = (const float*)d_in[6];
    const float* b2    = (const float*)d_in[7];
    float* out = (float*)d_out;

    char* ws = (char*)d_ws;
    int*   tokE = (int*)(ws + 0);                         // 32768 B
    float* tokG = (float*)(ws + 32768);                   // 32768 B
    int*   tokR = (int*)(ws + 65536);                     // 16384 B
    int*   sot  = (int*)(ws + 81920);                     // 32768 B
    int*   tos  = (int*)(ws + 114688);                    // 32768 B
    unsigned short* xe  = (unsigned short*)(ws + 147456);     // 16 MiB
    unsigned short* act = (unsigned short*)(ws + 16924672);   // 45 MiB
    float* oute = (float*)(ws + 62013440);                    // 32 MiB; end ~95.6 MB

    hipMemsetAsync(sot, 0xFF, 65536, stream);  // sot + tos contiguous -> -1

    k_gate<<<NTOK / 4, 256, 0, stream>>>(x, route, gw, tokE, tokG, tokR);
    k_pos<<<E_ * B_, 256, 0, stream>>>(tokE, tokG, tokR, sot, tos);
    k_disp<<<NSLOT, 256, 0, stream>>>(x, tos, xe);
    k_ffn1<<<dim3(43, 8, 8), 256, 0, stream>>>(xe, w1, b1, mb, act);
    k_ffn2<<<dim3(8, 8, 8), 256, 0, stream>>>(act, w2, b2, oute);
    k_comb<<<NTOK, 256, 0, stream>>>(oute, sot, tokG, out);
}

// Round 2
// 385.794 us; speedup vs baseline: 3.9811x; 3.9811x over previous
//
#include <hip/hip_runtime.h>
#include <hip/hip_bf16.h>

#define B_ 4
#define N_ 1024
#define D_ 1024
#define E_ 8
#define H_ 2730
#define H2_ 5460
#define CAP_ 256
#define NTOK 4096
#define NSLOT 8192
#define ACTP 2752   // H padded to multiple of 64

typedef __attribute__((ext_vector_type(8))) short short8;
typedef __attribute__((ext_vector_type(4))) float f32x4;

__device__ __forceinline__ unsigned short f2bf(float f) {
    __hip_bfloat16 h = __float2bfloat16(f);
    return *reinterpret_cast<unsigned short*>(&h);
}

// async global(16B/lane) -> LDS (wave-uniform base + lane*16)
#define GLL16(g, l)                                                          \
    __builtin_amdgcn_global_load_lds(                                        \
        (const __attribute__((address_space(1))) void*)(g),                  \
        (__attribute__((address_space(3))) void*)(l), 16, 0, 0)

// ---------------- weight conversion: w1 f32 [E][1024][5460] -> w1tv/w1tg bf16 [E][2752][1024] ----------------
__global__ __launch_bounds__(256) void k_cvt1(const float* __restrict__ w1,
                                              unsigned short* __restrict__ w1tv,
                                              unsigned short* __restrict__ w1tg) {
    const int ft = blockIdx.x;        // 0..85 (0..42 -> val, 43..85 -> gate)
    const int kt = blockIdx.y;        // 0..15
    const int e  = blockIdx.z;
    const int mat = (ft >= 43) ? 1 : 0;
    const int f0 = (ft - mat * 43) * 64;
    const int c0 = mat * H_ + f0;
    const int climit = mat * H_ + H_;
    const int k0 = kt * 64;
    const float* w1e = w1 + (size_t)e * D_ * H2_;
    __shared__ unsigned short tile[64][68];   // [col(local f)][row(local k)]
    const int rq = threadIdx.x >> 4, cq = threadIdx.x & 15;
    const bool fast = (c0 + 64 <= climit);
#pragma unroll
    for (int p = 0; p < 4; ++p) {
        int r = p * 16 + rq;
        int gk = k0 + r;
        const float* src = w1e + (size_t)gk * H2_ + c0 + cq * 4;
        float v0, v1, v2, v3;
        if (fast) {
            float2 u0 = *reinterpret_cast<const float2*>(src);
            float2 u1 = *reinterpret_cast<const float2*>(src + 2);
            v0 = u0.x; v1 = u0.y; v2 = u1.x; v3 = u1.y;
        } else {
            int cc = c0 + cq * 4;
            v0 = (cc + 0 < climit) ? src[0] : 0.f;
            v1 = (cc + 1 < climit) ? src[1] : 0.f;
            v2 = (cc + 2 < climit) ? src[2] : 0.f;
            v3 = (cc + 3 < climit) ? src[3] : 0.f;
        }
        tile[cq * 4 + 0][r] = f2bf(v0);
        tile[cq * 4 + 1][r] = f2bf(v1);
        tile[cq * 4 + 2][r] = f2bf(v2);
        tile[cq * 4 + 3][r] = f2bf(v3);
    }
    __syncthreads();
    unsigned short* dst = (mat ? w1tg : w1tv) + (size_t)e * ACTP * D_;
#pragma unroll
    for (int p = 0; p < 4; ++p) {
        int orow = p * 16 + rq;
        ushort4 o = *reinterpret_cast<const ushort4*>(&tile[orow][cq * 4]);
        *reinterpret_cast<ushort4*>(dst + (size_t)(f0 + orow) * D_ + k0 + cq * 4) = o;
    }
}

// ---------------- w2 f32 [E][2730][1024] -> w2t bf16 [E][1024][2752] (K zero-padded) ----------------
__global__ __launch_bounds__(256) void k_cvt2(const float* __restrict__ w2,
                                              unsigned short* __restrict__ w2t) {
    const int kt = blockIdx.x;        // 0..42 over ACTP
    const int dt = blockIdx.y;        // 0..15
    const int e  = blockIdx.z;
    const int k0 = kt * 64, d0 = dt * 64;
    const float* w2e = w2 + (size_t)e * H_ * D_;
    __shared__ unsigned short tile[64][68];   // [col(local d)][row(local k)]
    const int rq = threadIdx.x >> 4, cq = threadIdx.x & 15;
#pragma unroll
    for (int p = 0; p < 4; ++p) {
        int r = p * 16 + rq;
        int gk = k0 + r;
        float4 v;
        if (gk < H_) v = *reinterpret_cast<const float4*>(w2e + (size_t)gk * D_ + d0 + cq * 4);
        else { v.x = 0.f; v.y = 0.f; v.z = 0.f; v.w = 0.f; }
        tile[cq * 4 + 0][r] = f2bf(v.x);
        tile[cq * 4 + 1][r] = f2bf(v.y);
        tile[cq * 4 + 2][r] = f2bf(v.z);
        tile[cq * 4 + 3][r] = f2bf(v.w);
    }
    __syncthreads();
    unsigned short* dst = w2t + (size_t)e * D_ * ACTP;
#pragma unroll
    for (int p = 0; p < 4; ++p) {
        int orow = p * 16 + rq;
        ushort4 o = *reinterpret_cast<const ushort4*>(&tile[orow][cq * 4]);
        *reinterpret_cast<ushort4*>(dst + (size_t)(d0 + orow) * ACTP + k0 + cq * 4) = o;
    }
}

// ---------------- gating ----------------
__global__ __launch_bounds__(256) void k_gate(const float* __restrict__ x,
                                              const float* __restrict__ route,
                                              const float* __restrict__ gw,
                                              int* __restrict__ tokE,
                                              float* __restrict__ tokG,
                                              int* __restrict__ tokR) {
    const int wave = threadIdx.x >> 6, lane = threadIdx.x & 63;
    const int t = blockIdx.x * 4 + wave;
    float acc[E_];
#pragma unroll
    for (int e = 0; e < E_; ++e) acc[e] = 0.f;
    const float* xr = x + (size_t)t * D_;
    for (int d = lane; d < D_; d += 64) {
        float xv = xr[d];
        const float* g = gw + d * E_;
#pragma unroll
        for (int e = 0; e < E_; ++e) acc[e] = fmaf(xv, g[e], acc[e]);
    }
#pragma unroll
    for (int e = 0; e < E_; ++e) {
#pragma unroll
        for (int off = 32; off; off >>= 1) acc[e] += __shfl_xor(acc[e], off);
    }
    if (lane == 0) {
        float m = acc[0];
#pragma unroll
        for (int e = 1; e < E_; ++e) m = fmaxf(m, acc[e]);
        float p[E_]; float s = 0.f;
#pragma unroll
        for (int e = 0; e < E_; ++e) { p[e] = expf(acc[e] - m); s += p[e]; }
        int i0 = 0; float v0 = p[0];
#pragma unroll
        for (int e = 1; e < E_; ++e) if (p[e] > v0) { v0 = p[e]; i0 = e; }
        int i1 = (i0 == 0) ? 1 : 0; float v1 = p[i1];
#pragma unroll
        for (int e = 0; e < E_; ++e) if (e != i0 && p[e] > v1) { v1 = p[e]; i1 = e; }
        float p0 = v0 / s, p1 = v1 / s;
        float denom = fmaxf(p0 + p1, 1e-9f);
        float g0 = p0 / denom, g1 = p1 / denom;
        int r1 = route[NTOK + t] < (g1 / 0.2f);
        tokE[t] = i0; tokE[NTOK + t] = i1;
        tokG[t] = g0; tokG[NTOK + t] = g1;
        tokR[t] = r1;
    }
}

// ---------------- positions ----------------
__global__ __launch_bounds__(256) void k_pos(const int* __restrict__ tokE,
                                             const float* __restrict__ tokG,
                                             const int* __restrict__ tokR,
                                             int* __restrict__ sot,
                                             int* __restrict__ tos) {
    const int e = blockIdx.x & 7, b = blockIdx.x >> 3;
    const int t = threadIdx.x;
    __shared__ int sc[256];
    const int base_bt = b * N_ + t * 4;
    int m0[4], m1[4];
    int c0 = 0, c1 = 0;
#pragma unroll
    for (int i = 0; i < 4; ++i) {
        int bt = base_bt + i;
        m0[i] = (tokE[bt] == e) ? 1 : 0;
        m1[i] = ((tokE[NTOK + bt] == e) && tokR[bt]) ? 1 : 0;
        c0 += m0[i]; c1 += m1[i];
    }
    int packed = c0 | (c1 << 16);
    sc[t] = packed;
    __syncthreads();
    for (int off = 1; off < 256; off <<= 1) {
        int v = (t >= off) ? sc[t - off] : 0;
        __syncthreads();
        sc[t] += v;
        __syncthreads();
    }
    int incl = sc[t];
    int total = sc[255];
    int excl = incl - packed;
    int base0 = excl & 0xffff;
    int base1 = excl >> 16;
    int kept0 = min(total & 0xffff, CAP_);
#pragma unroll
    for (int i = 0; i < 4; ++i) {
        int bt = base_bt + i;
        if (m0[i]) {
            int pos = base0++;
            if (pos < CAP_ && tokG[bt] > 0.f) {
                int s = ((e * B_ + b) << 8) + pos;
                sot[bt] = s;
                tos[s] = bt;
            }
        }
        if (m1[i]) {
            int pos = (base1++) + kept0;
            if (pos < CAP_ && tokG[NTOK + bt] > 0.f) {
                int s = ((e * B_ + b) << 8) + pos;
                sot[NTOK + bt] = s;
                tos[s] = bt;
            }
        }
    }
}

// ---------------- dispatch ----------------
__global__ __launch_bounds__(256) void k_disp(const float* __restrict__ x,
                                              const int* __restrict__ tos,
                                              unsigned short* __restrict__ xe) {
    const int s = blockIdx.x;
    const int bt = tos[s];
    const int t = threadIdx.x;
    ushort4 o;
    if (bt >= 0) {
        const float4 v = *reinterpret_cast<const float4*>(x + (size_t)bt * D_ + t * 4);
        o.x = f2bf(v.x); o.y = f2bf(v.y); o.z = f2bf(v.z); o.w = f2bf(v.w);
    } else {
        o.x = 0; o.y = 0; o.z = 0; o.w = 0;
    }
    *reinterpret_cast<ushort4*>(xe + (size_t)s * D_ + t * 4) = o;
}

// ---------------- GEMM1 + GEGLU (m97 structure, global_load_lds staging) ----------------
__global__ __launch_bounds__(256) void k_ffn1(const unsigned short* __restrict__ xe,
                                              const unsigned short* __restrict__ w1tv,
                                              const unsigned short* __restrict__ w1tg,
                                              const float* __restrict__ b1,
                                              const float* __restrict__ mbias,
                                              unsigned short* __restrict__ act) {
    const int ct = blockIdx.x;   // 0..42: 64 f-cols
    const int rt = blockIdx.y;   // 0..7:  128 slot rows
    const int e  = blockIdx.z;
    const int jv = ct * 64;
    __shared__ unsigned short As[128 * 32];
    __shared__ unsigned short Bv[64 * 32];
    __shared__ unsigned short Bg[64 * 32];
    const int tid = threadIdx.x, lane = tid & 63, wv = tid >> 6;
    const int wr = wv >> 1, wc = wv & 1;

    f32x4 accv[4][2], accg[4][2];
#pragma unroll
    for (int i = 0; i < 4; ++i)
#pragma unroll
        for (int j = 0; j < 2; ++j) { accv[i][j] = (f32x4)(0.f); accg[i][j] = (f32x4)(0.f); }

    // staging roles: wv 0/1 -> A rows [wv*64, wv*64+64); wv 2 -> Bv; wv 3 -> Bg
    const int r16 = lane >> 2;              // row within 16-row instr group
    const int cseg = (lane & 3) * 8;        // 8 bf16 = 16 B
    const unsigned short* sw;
    char* lw;
    if (wv < 2) {
        sw = xe + ((size_t)(e * 1024 + rt * 128 + wv * 64 + r16)) * D_ + cseg;
        lw = (char*)As + wv * 4096;
    } else if (wv == 2) {
        sw = w1tv + (size_t)e * ACTP * D_ + (size_t)(jv + r16) * D_ + cseg;
        lw = (char*)Bv;
    } else {
        sw = w1tg + (size_t)e * ACTP * D_ + (size_t)(jv + r16) * D_ + cseg;
        lw = (char*)Bg;
    }

    const int frow = lane & 15, fk = (lane >> 4) * 8;

    for (int kk = 0; kk < 32; ++kk) {
        const unsigned short* s = sw + kk * 32;
#pragma unroll
        for (int i = 0; i < 4; ++i)
            GLL16(s + (size_t)i * 16 * D_, lw + i * 1024);
        __syncthreads();

        short8 bfv[2], bfg[2];
#pragma unroll
        for (int nc = 0; nc < 2; ++nc) {
            bfv[nc] = *reinterpret_cast<const short8*>(&Bv[(wc * 32 + nc * 16 + frow) * 32 + fk]);
            bfg[nc] = *reinterpret_cast<const short8*>(&Bg[(wc * 32 + nc * 16 + frow) * 32 + fk]);
        }
#pragma unroll
        for (int mr = 0; mr < 4; ++mr) {
            short8 af = *reinterpret_cast<const short8*>(&As[(wr * 64 + mr * 16 + frow) * 32 + fk]);
#pragma unroll
            for (int nc = 0; nc < 2; ++nc) {
                accv[mr][nc] = __builtin_amdgcn_mfma_f32_16x16x32_bf16(af, bfv[nc], accv[mr][nc], 0, 0, 0);
                accg[mr][nc] = __builtin_amdgcn_mfma_f32_16x16x32_bf16(af, bfg[nc], accg[mr][nc], 0, 0, 0);
            }
        }
        __syncthreads();
    }

    const float* b1e = b1 + (size_t)e * H2_;
    const float* mbe = mbias + (size_t)e * H_;
    const int col = lane & 15, rowq = (lane >> 4) * 4;
    const int Rbase = rt * 128 + wr * 64;
#pragma unroll
    for (int mr = 0; mr < 4; ++mr) {
#pragma unroll
        for (int nc = 0; nc < 2; ++nc) {
            int f = jv + wc * 32 + nc * 16 + col;
#pragma unroll
            for (int j = 0; j < 4; ++j) {
                int R = Rbase + mr * 16 + rowq + j;
                size_t o = ((size_t)(e * 1024 + R)) * ACTP + f;
                if (f < H_) {
                    float val = accv[mr][nc][j] + b1e[f];
                    float gt  = accg[mr][nc][j] + b1e[H_ + f];
                    float a = 0.5f * gt * (1.f + erff(gt * 0.70710678118654752f)) * val * mbe[f];
                    act[o] = f2bf(a);
                } else {
                    act[o] = 0;
                }
            }
        }
    }
}

// ---------------- GEMM2 (m97 structure) ----------------
__global__ __launch_bounds__(256) void k_ffn2(const unsigned short* __restrict__ act,
                                              const unsigned short* __restrict__ w2t,
                                              const float* __restrict__ b2,
                                              float* __restrict__ oute) {
    const int nt = blockIdx.x;   // 0..7: 128 d-cols
    const int mt = blockIdx.y;   // 0..7: 128 slot rows
    const int e  = blockIdx.z;
    __shared__ unsigned short As[128 * 32];
    __shared__ unsigned short Bs[128 * 32];
    const int tid = threadIdx.x, lane = tid & 63, wv = tid >> 6;
    const int wr = wv >> 1, wc = wv & 1;

    f32x4 acc[4][4];
#pragma unroll
    for (int i = 0; i < 4; ++i)
#pragma unroll
        for (int j = 0; j < 4; ++j) acc[i][j] = (f32x4)(0.f);

    const int r16 = lane >> 2;
    const int cseg = (lane & 3) * 8;
    const unsigned short* sw;
    char* lw;
    if (wv < 2) {
        sw = act + ((size_t)(e * 1024 + mt * 128 + wv * 64 + r16)) * ACTP + cseg;
        lw = (char*)As + wv * 4096;
    } else {
        sw = w2t + (size_t)e * D_ * ACTP + (size_t)(nt * 128 + (wv - 2) * 64 + r16) * ACTP + cseg;
        lw = (char*)Bs + (wv - 2) * 4096;
    }

    const int frow = lane & 15, fk = (lane >> 4) * 8;

    for (int kk = 0; kk < 86; ++kk) {
        const unsigned short* s = sw + kk * 32;
#pragma unroll
        for (int i = 0; i < 4; ++i)
            GLL16(s + (size_t)i * 16 * ACTP, lw + i * 1024);
        __syncthreads();

        short8 af[4], bf[4];
#pragma unroll
        for (int mr = 0; mr < 4; ++mr)
            af[mr] = *reinterpret_cast<const short8*>(&As[(wr * 64 + mr * 16 + frow) * 32 + fk]);
#pragma unroll
        for (int nc = 0; nc < 4; ++nc)
            bf[nc] = *reinterpret_cast<const short8*>(&Bs[(wc * 64 + nc * 16 + frow) * 32 + fk]);
#pragma unroll
        for (int mr = 0; mr < 4; ++mr)
#pragma unroll
            for (int nc = 0; nc < 4; ++nc)
                acc[mr][nc] = __builtin_amdgcn_mfma_f32_16x16x32_bf16(af[mr], bf[nc], acc[mr][nc], 0, 0, 0);
        __syncthreads();
    }

    const float* b2e = b2 + (size_t)e * D_;
    const int col = lane & 15, rowq = (lane >> 4) * 4;
#pragma unroll
    for (int mr = 0; mr < 4; ++mr) {
#pragma unroll
        for (int nc = 0; nc < 4; ++nc) {
            int d = nt * 128 + wc * 64 + nc * 16 + col;
#pragma unroll
            for (int j = 0; j < 4; ++j) {
                int R = mt * 128 + wr * 64 + mr * 16 + rowq + j;
                oute[((size_t)(e * 1024 + R)) * D_ + d] = acc[mr][nc][j] + b2e[d];
            }
        }
    }
}

// ---------------- combine ----------------
__global__ __launch_bounds__(256) void k_comb(const float* __restrict__ oute,
                                              const int* __restrict__ sot,
                                              const float* __restrict__ tokG,
                                              float* __restrict__ out) {
    const int bt = blockIdx.x;
    const int t = threadIdx.x;
    const int s0 = sot[bt], s1 = sot[NTOK + bt];
    const float g0 = tokG[bt], g1 = tokG[NTOK + bt];
    float r0 = 0.f, r1 = 0.f, r2 = 0.f, r3 = 0.f;
    if (s0 >= 0) {
        const float4 v = *reinterpret_cast<const float4*>(oute + (size_t)s0 * D_ + t * 4);
        r0 += g0 * v.x; r1 += g0 * v.y; r2 += g0 * v.z; r3 += g0 * v.w;
    }
    if (s1 >= 0) {
        const float4 v = *reinterpret_cast<const float4*>(oute + (size_t)s1 * D_ + t * 4);
        r0 += g1 * v.x; r1 += g1 * v.y; r2 += g1 * v.z; r3 += g1 * v.w;
    }
    float4 o; o.x = r0; o.y = r1; o.z = r2; o.w = r3;
    *reinterpret_cast<float4*>(out + (size_t)bt * D_ + t * 4) = o;
}

extern "C" void kernel_launch(void* const* d_in, const int* in_sizes, int n_in,
                              void* d_out, int out_size, void* d_ws, size_t ws_size,
                              hipStream_t stream) {
    const float* x     = (const float*)d_in[0];
    const float* route = (const float*)d_in[1];
    const float* gw    = (const float*)d_in[2];
    const float* w1    = (const float*)d_in[3];
    const float* b1    = (const float*)d_in[4];
    const float* mb    = (const float*)d_in[5];
    const float* w2    = (const float*)d_in[6];
    const float* b2    = (const float*)d_in[7];
    float* out = (float*)d_out;

    char* ws = (char*)d_ws;
    int*   tokE = (int*)(ws + 0);
    float* tokG = (float*)(ws + 32768);
    int*   tokR = (int*)(ws + 65536);
    int*   sot  = (int*)(ws + 81920);
    int*   tos  = (int*)(ws + 114688);
    unsigned short* xe   = (unsigned short*)(ws + 147456);      // 16 MiB, end 16,924,672
    unsigned short* act  = (unsigned short*)(ws + 16924672);    // 45 MiB, end 62,013,440
    unsigned short* w1tv = (unsigned short*)(ws + 62013440);    // 45 MiB, end 107,102,208
    unsigned short* w1tg = (unsigned short*)(ws + 107102208);   // 45 MiB, end 152,190,976
    unsigned short* w2t  = (unsigned short*)(ws + 152190976);   // 45 MiB, end 197,279,744
    float* oute = (float*)(ws + 62013440);  // 32 MiB overlay on w1tv (dead after k_ffn1)

    hipMemsetAsync(sot, 0xFF, 65536, stream);  // sot + tos -> -1

    k_cvt1<<<dim3(86, 16, 8), 256, 0, stream>>>(w1, w1tv, w1tg);
    k_cvt2<<<dim3(43, 16, 8), 256, 0, stream>>>(w2, w2t);
    k_gate<<<NTOK / 4, 256, 0, stream>>>(x, route, gw, tokE, tokG, tokR);
    k_pos<<<E_ * B_, 256, 0, stream>>>(tokE, tokG, tokR, sot, tos);
    k_disp<<<NSLOT, 256, 0, stream>>>(x, tos, xe);
    k_ffn1<<<dim3(43, 8, 8), 256, 0, stream>>>(xe, w1tv, w1tg, b1, mb, act);
    k_ffn2<<<dim3(8, 8, 8), 256, 0, stream>>>(act, w2t, b2, oute);
    k_comb<<<NTOK, 256, 0, stream>>>(oute, sot, tokG, out);
}

// Round 3
// 361.538 us; speedup vs baseline: 4.2482x; 1.0671x over previous
//
#include <hip/hip_runtime.h>
#include <hip/hip_bf16.h>

#define B_ 4
#define N_ 1024
#define D_ 1024
#define E_ 8
#define H_ 2730
#define H2_ 5460
#define CAP_ 256
#define NTOK 4096
#define NSLOT 8192
#define ACTP 2752   // H padded to multiple of 64

typedef __attribute__((ext_vector_type(8))) short short8;
typedef __attribute__((ext_vector_type(4))) float f32x4;

__device__ __forceinline__ unsigned short f2bf(float f) {
    __hip_bfloat16 h = __float2bfloat16(f);
    return *reinterpret_cast<unsigned short*>(&h);
}

// async global(16B/lane) -> LDS (wave-uniform base + lane*16)
#define GLL16(g, l)                                                          \
    __builtin_amdgcn_global_load_lds(                                        \
        (const __attribute__((address_space(1))) void*)(g),                  \
        (__attribute__((address_space(3))) void*)(l), 16, 0, 0)

// ---------------- weight conversion: w1 f32 [E][1024][5460] -> w1tv/w1tg bf16 [E][2752][1024] ----------------
__global__ __launch_bounds__(256) void k_cvt1(const float* __restrict__ w1,
                                              unsigned short* __restrict__ w1tv,
                                              unsigned short* __restrict__ w1tg) {
    const int ft = blockIdx.x;        // 0..85 (0..42 -> val, 43..85 -> gate)
    const int kt = blockIdx.y;        // 0..15
    const int e  = blockIdx.z;
    const int mat = (ft >= 43) ? 1 : 0;
    const int f0 = (ft - mat * 43) * 64;
    const int c0 = mat * H_ + f0;
    const int climit = mat * H_ + H_;
    const int k0 = kt * 64;
    const float* w1e = w1 + (size_t)e * D_ * H2_;
    __shared__ unsigned short tile[64][68];   // [col(local f)][row(local k)]
    const int rq = threadIdx.x >> 4, cq = threadIdx.x & 15;
    const bool fast = (c0 + 64 <= climit);
#pragma unroll
    for (int p = 0; p < 4; ++p) {
        int r = p * 16 + rq;
        int gk = k0 + r;
        const float* src = w1e + (size_t)gk * H2_ + c0 + cq * 4;
        float v0, v1, v2, v3;
        if (fast) {
            float2 u0 = *reinterpret_cast<const float2*>(src);
            float2 u1 = *reinterpret_cast<const float2*>(src + 2);
            v0 = u0.x; v1 = u0.y; v2 = u1.x; v3 = u1.y;
        } else {
            int cc = c0 + cq * 4;
            v0 = (cc + 0 < climit) ? src[0] : 0.f;
            v1 = (cc + 1 < climit) ? src[1] : 0.f;
            v2 = (cc + 2 < climit) ? src[2] : 0.f;
            v3 = (cc + 3 < climit) ? src[3] : 0.f;
        }
        tile[cq * 4 + 0][r] = f2bf(v0);
        tile[cq * 4 + 1][r] = f2bf(v1);
        tile[cq * 4 + 2][r] = f2bf(v2);
        tile[cq * 4 + 3][r] = f2bf(v3);
    }
    __syncthreads();
    unsigned short* dst = (mat ? w1tg : w1tv) + (size_t)e * ACTP * D_;
#pragma unroll
    for (int p = 0; p < 4; ++p) {
        int orow = p * 16 + rq;
        ushort4 o = *reinterpret_cast<const ushort4*>(&tile[orow][cq * 4]);
        *reinterpret_cast<ushort4*>(dst + (size_t)(f0 + orow) * D_ + k0 + cq * 4) = o;
    }
}

// ---------------- w2 f32 [E][2730][1024] -> w2t bf16 [E][1024][2752] (K zero-padded) ----------------
__global__ __launch_bounds__(256) void k_cvt2(const float* __restrict__ w2,
                                              unsigned short* __restrict__ w2t) {
    const int kt = blockIdx.x;        // 0..42 over ACTP
    const int dt = blockIdx.y;        // 0..15
    const int e  = blockIdx.z;
    const int k0 = kt * 64, d0 = dt * 64;
    const float* w2e = w2 + (size_t)e * H_ * D_;
    __shared__ unsigned short tile[64][68];   // [col(local d)][row(local k)]
    const int rq = threadIdx.x >> 4, cq = threadIdx.x & 15;
#pragma unroll
    for (int p = 0; p < 4; ++p) {
        int r = p * 16 + rq;
        int gk = k0 + r;
        float4 v;
        if (gk < H_) v = *reinterpret_cast<const float4*>(w2e + (size_t)gk * D_ + d0 + cq * 4);
        else { v.x = 0.f; v.y = 0.f; v.z = 0.f; v.w = 0.f; }
        tile[cq * 4 + 0][r] = f2bf(v.x);
        tile[cq * 4 + 1][r] = f2bf(v.y);
        tile[cq * 4 + 2][r] = f2bf(v.z);
        tile[cq * 4 + 3][r] = f2bf(v.w);
    }
    __syncthreads();
    unsigned short* dst = w2t + (size_t)e * D_ * ACTP;
#pragma unroll
    for (int p = 0; p < 4; ++p) {
        int orow = p * 16 + rq;
        ushort4 o = *reinterpret_cast<const ushort4*>(&tile[orow][cq * 4]);
        *reinterpret_cast<ushort4*>(dst + (size_t)(d0 + orow) * ACTP + k0 + cq * 4) = o;
    }
}

// ---------------- gating ----------------
__global__ __launch_bounds__(256) void k_gate(const float* __restrict__ x,
                                              const float* __restrict__ route,
                                              const float* __restrict__ gw,
                                              int* __restrict__ tokE,
                                              float* __restrict__ tokG,
                                              int* __restrict__ tokR) {
    const int wave = threadIdx.x >> 6, lane = threadIdx.x & 63;
    const int t = blockIdx.x * 4 + wave;
    float acc[E_];
#pragma unroll
    for (int e = 0; e < E_; ++e) acc[e] = 0.f;
    const float* xr = x + (size_t)t * D_;
    for (int d = lane; d < D_; d += 64) {
        float xv = xr[d];
        const float* g = gw + d * E_;
#pragma unroll
        for (int e = 0; e < E_; ++e) acc[e] = fmaf(xv, g[e], acc[e]);
    }
#pragma unroll
    for (int e = 0; e < E_; ++e) {
#pragma unroll
        for (int off = 32; off; off >>= 1) acc[e] += __shfl_xor(acc[e], off);
    }
    if (lane == 0) {
        float m = acc[0];
#pragma unroll
        for (int e = 1; e < E_; ++e) m = fmaxf(m, acc[e]);
        float p[E_]; float s = 0.f;
#pragma unroll
        for (int e = 0; e < E_; ++e) { p[e] = expf(acc[e] - m); s += p[e]; }
        int i0 = 0; float v0 = p[0];
#pragma unroll
        for (int e = 1; e < E_; ++e) if (p[e] > v0) { v0 = p[e]; i0 = e; }
        int i1 = (i0 == 0) ? 1 : 0; float v1 = p[i1];
#pragma unroll
        for (int e = 0; e < E_; ++e) if (e != i0 && p[e] > v1) { v1 = p[e]; i1 = e; }
        float p0 = v0 / s, p1 = v1 / s;
        float denom = fmaxf(p0 + p1, 1e-9f);
        float g0 = p0 / denom, g1 = p1 / denom;
        int r1 = route[NTOK + t] < (g1 / 0.2f);
        tokE[t] = i0; tokE[NTOK + t] = i1;
        tokG[t] = g0; tokG[NTOK + t] = g1;
        tokR[t] = r1;
    }
}

// ---------------- positions ----------------
__global__ __launch_bounds__(256) void k_pos(const int* __restrict__ tokE,
                                             const float* __restrict__ tokG,
                                             const int* __restrict__ tokR,
                                             int* __restrict__ sot,
                                             int* __restrict__ tos) {
    const int e = blockIdx.x & 7, b = blockIdx.x >> 3;
    const int t = threadIdx.x;
    __shared__ int sc[256];
    const int base_bt = b * N_ + t * 4;
    int m0[4], m1[4];
    int c0 = 0, c1 = 0;
#pragma unroll
    for (int i = 0; i < 4; ++i) {
        int bt = base_bt + i;
        m0[i] = (tokE[bt] == e) ? 1 : 0;
        m1[i] = ((tokE[NTOK + bt] == e) && tokR[bt]) ? 1 : 0;
        c0 += m0[i]; c1 += m1[i];
    }
    int packed = c0 | (c1 << 16);
    sc[t] = packed;
    __syncthreads();
    for (int off = 1; off < 256; off <<= 1) {
        int v = (t >= off) ? sc[t - off] : 0;
        __syncthreads();
        sc[t] += v;
        __syncthreads();
    }
    int incl = sc[t];
    int total = sc[255];
    int excl = incl - packed;
    int base0 = excl & 0xffff;
    int base1 = excl >> 16;
    int kept0 = min(total & 0xffff, CAP_);
#pragma unroll
    for (int i = 0; i < 4; ++i) {
        int bt = base_bt + i;
        if (m0[i]) {
            int pos = base0++;
            if (pos < CAP_ && tokG[bt] > 0.f) {
                int s = ((e * B_ + b) << 8) + pos;
                sot[bt] = s;
                tos[s] = bt;
            }
        }
        if (m1[i]) {
            int pos = (base1++) + kept0;
            if (pos < CAP_ && tokG[NTOK + bt] > 0.f) {
                int s = ((e * B_ + b) << 8) + pos;
                sot[NTOK + bt] = s;
                tos[s] = bt;
            }
        }
    }
}

// ---------------- dispatch ----------------
__global__ __launch_bounds__(256) void k_disp(const float* __restrict__ x,
                                              const int* __restrict__ tos,
                                              unsigned short* __restrict__ xe) {
    const int s = blockIdx.x;
    const int bt = tos[s];
    const int t = threadIdx.x;
    ushort4 o;
    if (bt >= 0) {
        const float4 v = *reinterpret_cast<const float4*>(x + (size_t)bt * D_ + t * 4);
        o.x = f2bf(v.x); o.y = f2bf(v.y); o.z = f2bf(v.z); o.w = f2bf(v.w);
    } else {
        o.x = 0; o.y = 0; o.z = 0; o.w = 0;
    }
    *reinterpret_cast<ushort4*>(xe + (size_t)s * D_ + t * 4) = o;
}

// ---------------- GEMM1 + GEGLU: 2-phase double-buffered, XCD-chunked ----------------
__global__ __launch_bounds__(256) void k_ffn1(const unsigned short* __restrict__ xe,
                                              const unsigned short* __restrict__ w1tv,
                                              const unsigned short* __restrict__ w1tg,
                                              const float* __restrict__ b1,
                                              const float* __restrict__ mbias,
                                              unsigned short* __restrict__ act) {
    // bijective XCD chunking: 2752 = 8 * 344; one expert per XCD; rt fastest
    const int wg = blockIdx.x;
    const int nid = (wg & 7) * 344 + (wg >> 3);
    const int e  = nid / 344;
    const int rem = nid % 344;
    const int ct = rem >> 3;     // 0..42: 64 f-cols (B panel shared by 8 consecutive blocks)
    const int rt = rem & 7;      // 0..7: 128 slot rows
    const int jv = ct * 64;

    __shared__ unsigned short As[2][128 * 32];
    __shared__ unsigned short Bv[2][64 * 32];
    __shared__ unsigned short Bg[2][64 * 32];
    const int tid = threadIdx.x, lane = tid & 63, wv = tid >> 6;
    const int wr = wv >> 1, wc = wv & 1;

    f32x4 accv[4][2], accg[4][2];
#pragma unroll
    for (int i = 0; i < 4; ++i)
#pragma unroll
        for (int j = 0; j < 2; ++j) { accv[i][j] = (f32x4)(0.f); accg[i][j] = (f32x4)(0.f); }

    // staging roles: wv 0/1 -> A rows; wv 2 -> Bv; wv 3 -> Bg
    const int r16 = lane >> 2;
    const int cseg = (lane & 3) * 8;
    const unsigned short* sw;
    char* lw0;
    int lstr;
    if (wv < 2) {
        sw = xe + ((size_t)(e * 1024 + rt * 128 + wv * 64 + r16)) * D_ + cseg;
        lw0 = (char*)&As[0][0] + wv * 4096;
        lstr = 128 * 32 * 2;
    } else if (wv == 2) {
        sw = w1tv + (size_t)e * ACTP * D_ + (size_t)(jv + r16) * D_ + cseg;
        lw0 = (char*)&Bv[0][0];
        lstr = 64 * 32 * 2;
    } else {
        sw = w1tg + (size_t)e * ACTP * D_ + (size_t)(jv + r16) * D_ + cseg;
        lw0 = (char*)&Bg[0][0];
        lstr = 64 * 32 * 2;
    }

    const int frow = lane & 15, fk = (lane >> 4) * 8;

    // prologue: stage tile 0 into buffer 0
    {
        const unsigned short* s = sw;
#pragma unroll
        for (int i = 0; i < 4; ++i)
            GLL16(s + (size_t)i * 16 * D_, lw0 + i * 1024);
    }
    __syncthreads();

    int cur = 0;
    for (int kk = 0; kk < 32; ++kk) {
        if (kk + 1 < 32) {  // issue next tile's loads into the other buffer (overlaps MFMA below)
            const unsigned short* s = sw + (kk + 1) * 32;
            char* l = lw0 + (cur ^ 1) * lstr;
#pragma unroll
            for (int i = 0; i < 4; ++i)
                GLL16(s + (size_t)i * 16 * D_, l + i * 1024);
        }

        short8 bfv[2], bfg[2];
#pragma unroll
        for (int nc = 0; nc < 2; ++nc) {
            bfv[nc] = *reinterpret_cast<const short8*>(&Bv[cur][(wc * 32 + nc * 16 + frow) * 32 + fk]);
            bfg[nc] = *reinterpret_cast<const short8*>(&Bg[cur][(wc * 32 + nc * 16 + frow) * 32 + fk]);
        }
#pragma unroll
        for (int mr = 0; mr < 4; ++mr) {
            short8 af = *reinterpret_cast<const short8*>(&As[cur][(wr * 64 + mr * 16 + frow) * 32 + fk]);
#pragma unroll
            for (int nc = 0; nc < 2; ++nc) {
                accv[mr][nc] = __builtin_amdgcn_mfma_f32_16x16x32_bf16(af, bfv[nc], accv[mr][nc], 0, 0, 0);
                accg[mr][nc] = __builtin_amdgcn_mfma_f32_16x16x32_bf16(af, bfg[nc], accg[mr][nc], 0, 0, 0);
            }
        }
        __syncthreads();   // drains vmcnt for the prefetch issued above (after a full MFMA phase)
        cur ^= 1;
    }

    const float* b1e = b1 + (size_t)e * H2_;
    const float* mbe = mbias + (size_t)e * H_;
    const int col = lane & 15, rowq = (lane >> 4) * 4;
    const int Rbase = rt * 128 + wr * 64;
#pragma unroll
    for (int mr = 0; mr < 4; ++mr) {
#pragma unroll
        for (int nc = 0; nc < 2; ++nc) {
            int f = jv + wc * 32 + nc * 16 + col;
#pragma unroll
            for (int j = 0; j < 4; ++j) {
                int R = Rbase + mr * 16 + rowq + j;
                size_t o = ((size_t)(e * 1024 + R)) * ACTP + f;
                if (f < H_) {
                    float val = accv[mr][nc][j] + b1e[f];
                    float gt  = accg[mr][nc][j] + b1e[H_ + f];
                    float a = 0.5f * gt * (1.f + erff(gt * 0.70710678118654752f)) * val * mbe[f];
                    act[o] = f2bf(a);
                } else {
                    act[o] = 0;
                }
            }
        }
    }
}

// ---------------- GEMM2: 2-phase double-buffered, XCD-chunked ----------------
__global__ __launch_bounds__(256) void k_ffn2(const unsigned short* __restrict__ act,
                                              const unsigned short* __restrict__ w2t,
                                              const float* __restrict__ b2,
                                              float* __restrict__ oute) {
    // 512 = 8 * 64; one expert per XCD; mt fastest (8 blocks share B panel)
    const int wg = blockIdx.x;
    const int nid = (wg & 7) * 64 + (wg >> 3);
    const int e  = nid >> 6;
    const int rem = nid & 63;
    const int nt = rem >> 3;   // 0..7: 128 d-cols
    const int mt = rem & 7;    // 0..7: 128 slot rows

    __shared__ unsigned short As[2][128 * 32];
    __shared__ unsigned short Bs[2][128 * 32];
    const int tid = threadIdx.x, lane = tid & 63, wv = tid >> 6;
    const int wr = wv >> 1, wc = wv & 1;

    f32x4 acc[4][4];
#pragma unroll
    for (int i = 0; i < 4; ++i)
#pragma unroll
        for (int j = 0; j < 4; ++j) acc[i][j] = (f32x4)(0.f);

    const int r16 = lane >> 2;
    const int cseg = (lane & 3) * 8;
    const unsigned short* sw;
    char* lw0;
    const int lstr = 128 * 32 * 2;
    if (wv < 2) {
        sw = act + ((size_t)(e * 1024 + mt * 128 + wv * 64 + r16)) * ACTP + cseg;
        lw0 = (char*)&As[0][0] + wv * 4096;
    } else {
        sw = w2t + (size_t)e * D_ * ACTP + (size_t)(nt * 128 + (wv - 2) * 64 + r16) * ACTP + cseg;
        lw0 = (char*)&Bs[0][0] + (wv - 2) * 4096;
    }

    const int frow = lane & 15, fk = (lane >> 4) * 8;

    {
        const unsigned short* s = sw;
#pragma unroll
        for (int i = 0; i < 4; ++i)
            GLL16(s + (size_t)i * 16 * ACTP, lw0 + i * 1024);
    }
    __syncthreads();

    int cur = 0;
    for (int kk = 0; kk < 86; ++kk) {
        if (kk + 1 < 86) {
            const unsigned short* s = sw + (kk + 1) * 32;
            char* l = lw0 + (cur ^ 1) * lstr;
#pragma unroll
            for (int i = 0; i < 4; ++i)
                GLL16(s + (size_t)i * 16 * ACTP, l + i * 1024);
        }

        short8 af[4], bf[4];
#pragma unroll
        for (int mr = 0; mr < 4; ++mr)
            af[mr] = *reinterpret_cast<const short8*>(&As[cur][(wr * 64 + mr * 16 + frow) * 32 + fk]);
#pragma unroll
        for (int nc = 0; nc < 4; ++nc)
            bf[nc] = *reinterpret_cast<const short8*>(&Bs[cur][(wc * 64 + nc * 16 + frow) * 32 + fk]);
#pragma unroll
        for (int mr = 0; mr < 4; ++mr)
#pragma unroll
            for (int nc = 0; nc < 4; ++nc)
                acc[mr][nc] = __builtin_amdgcn_mfma_f32_16x16x32_bf16(af[mr], bf[nc], acc[mr][nc], 0, 0, 0);
        __syncthreads();
        cur ^= 1;
    }

    const float* b2e = b2 + (size_t)e * D_;
    const int col = lane & 15, rowq = (lane >> 4) * 4;
#pragma unroll
    for (int mr = 0; mr < 4; ++mr) {
#pragma unroll
        for (int nc = 0; nc < 4; ++nc) {
            int d = nt * 128 + wc * 64 + nc * 16 + col;
#pragma unroll
            for (int j = 0; j < 4; ++j) {
                int R = mt * 128 + wr * 64 + mr * 16 + rowq + j;
                oute[((size_t)(e * 1024 + R)) * D_ + d] = acc[mr][nc][j] + b2e[d];
            }
        }
    }
}

// ---------------- combine ----------------
__global__ __launch_bounds__(256) void k_comb(const float* __restrict__ oute,
                                              const int* __restrict__ sot,
                                              const float* __restrict__ tokG,
                                              float* __restrict__ out) {
    const int bt = blockIdx.x;
    const int t = threadIdx.x;
    const int s0 = sot[bt], s1 = sot[NTOK + bt];
    const float g0 = tokG[bt], g1 = tokG[NTOK + bt];
    float r0 = 0.f, r1 = 0.f, r2 = 0.f, r3 = 0.f;
    if (s0 >= 0) {
        const float4 v = *reinterpret_cast<const float4*>(oute + (size_t)s0 * D_ + t * 4);
        r0 += g0 * v.x; r1 += g0 * v.y; r2 += g0 * v.z; r3 += g0 * v.w;
    }
    if (s1 >= 0) {
        const float4 v = *reinterpret_cast<const float4*>(oute + (size_t)s1 * D_ + t * 4);
        r0 += g1 * v.x; r1 += g1 * v.y; r2 += g1 * v.z; r3 += g1 * v.w;
    }
    float4 o; o.x = r0; o.y = r1; o.z = r2; o.w = r3;
    *reinterpret_cast<float4*>(out + (size_t)bt * D_ + t * 4) = o;
}

extern "C" void kernel_launch(void* const* d_in, const int* in_sizes, int n_in,
                              void* d_out, int out_size, void* d_ws, size_t ws_size,
                              hipStream_t stream) {
    const float* x     = (const float*)d_in[0];
    const float* route = (const float*)d_in[1];
    const float* gw    = (const float*)d_in[2];
    const float* w1    = (const float*)d_in[3];
    const float* b1    = (const float*)d_in[4];
    const float* mb    = (const float*)d_in[5];
    const float* w2    = (const float*)d_in[6];
    const float* b2    = (const float*)d_in[7];
    float* out = (float*)d_out;

    char* ws = (char*)d_ws;
    int*   tokE = (int*)(ws + 0);
    float* tokG = (float*)(ws + 32768);
    int*   tokR = (int*)(ws + 65536);
    int*   sot  = (int*)(ws + 81920);
    int*   tos  = (int*)(ws + 114688);
    unsigned short* xe   = (unsigned short*)(ws + 147456);      // 16 MiB, end 16,924,672
    unsigned short* act  = (unsigned short*)(ws + 16924672);    // 45 MiB, end 62,013,440
    unsigned short* w1tv = (unsigned short*)(ws + 62013440);    // 45 MiB, end 107,102,208
    unsigned short* w1tg = (unsigned short*)(ws + 107102208);   // 45 MiB, end 152,190,976
    unsigned short* w2t  = (unsigned short*)(ws + 152190976);   // 45 MiB, end 197,279,744
    float* oute = (float*)(ws + 62013440);  // 32 MiB overlay on w1tv (dead after k_ffn1)

    hipMemsetAsync(sot, 0xFF, 65536, stream);  // sot + tos -> -1

    k_cvt1<<<dim3(86, 16, 8), 256, 0, stream>>>(w1, w1tv, w1tg);
    k_cvt2<<<dim3(43, 16, 8), 256, 0, stream>>>(w2, w2t);
    k_gate<<<NTOK / 4, 256, 0, stream>>>(x, route, gw, tokE, tokG, tokR);
    k_pos<<<E_ * B_, 256, 0, stream>>>(tokE, tokG, tokR, sot, tos);
    k_disp<<<NSLOT, 256, 0, stream>>>(x, tos, xe);
    k_ffn1<<<2752, 256, 0, stream>>>(xe, w1tv, w1tg, b1, mb, act);
    k_ffn2<<<512, 256, 0, stream>>>(act, w2t, b2, oute);
    k_comb<<<NTOK, 256, 0, stream>>>(oute, sot, tokG, out);
}

// Round 4
// 361.334 us; speedup vs baseline: 4.2506x; 1.0006x over previous
//
#include <hip/hip_runtime.h>
#include <hip/hip_bf16.h>
#include <math.h>

#define B_ 4
#define N_ 1024
#define D_ 1024
#define E_ 8
#define H_ 2730
#define H2_ 5460
#define CAP_ 256
#define NTOK 4096
#define NSLOT 8192
#define NKT1 16      // K-tiles for GEMM1 (K=1024, BK=64)
#define NKT2 43      // K-tiles for GEMM2 (K=2752, BK=64)
#define NFG 22       // 128-wide f-col groups (pad 2816)

typedef __attribute__((ext_vector_type(8))) short short8;
typedef __attribute__((ext_vector_type(4))) float f32x4;

__device__ __forceinline__ unsigned short f2bf(float f) {
    __hip_bfloat16 h = __float2bfloat16(f);
    return *reinterpret_cast<unsigned short*>(&h);
}

// async global(16B/lane) -> LDS (wave-uniform base + lane*16)
#define GLL16(g, l)                                                          \
    __builtin_amdgcn_global_load_lds(                                        \
        (const __attribute__((address_space(1))) void*)(g),                  \
        (__attribute__((address_space(3))) void*)(l), 16, 0, 0)

// ============ fragment-packed layouts ============
// A-type chunk (per (sgrp,kt), 16384 ushorts = 32KB):
//   off = k32*8192 + m16*512 + lane*8 + b ; elem = A[sgrp*256 + m16*16 + (lane&15)][kt*64 + k32*32 + (lane>>4)*8 + b]
// B1 chunk (per (e,fg,kt), 16384 ush): off = k32*8192 + n16*512 + lane*8 + b
//   n16 0..7: val f = fg*128+(n16&7)*16+(lane&15); n16 8..15: gate same f
// B2 chunk (per (e,nt,kt), 8192 ush): off = k32*4096 + n16*512 + lane*8 + b
//   d = nt*128 + n16*16 + (lane&15); k = f-dim

// ---------------- cvt1: w1 f32 -> fragment-packed bf16 B-panel (val+gate) ----------------
__global__ __launch_bounds__(256) void k_cvt1(const float* __restrict__ w1,
                                              unsigned short* __restrict__ w1p) {
    const int fg = blockIdx.x;   // 0..21
    const int kt = blockIdx.y;   // 0..15
    const int e  = blockIdx.z;
    const float* w1e = w1 + (size_t)e * D_ * H2_;
    unsigned short* dst = w1p + (((size_t)((e * NFG + fg) * NKT1 + kt)) << 14);
#pragma unroll
    for (int i = 0; i < 8; ++i) {
        const int o = i * 256 + threadIdx.x;        // 0..2047 16B-blocks
        const int l = o & 63, n16 = (o >> 6) & 15, k32 = o >> 10;
        const int f = fg * 128 + ((n16 & 7) << 4) + (l & 15);
        const int k = kt * 64 + (k32 << 5) + ((l >> 4) << 3);
        ushort4 r0 = {0, 0, 0, 0}, r1 = {0, 0, 0, 0};
        if (f < H_) {
            const float* s = w1e + (size_t)k * H2_ + (n16 >= 8 ? H_ : 0) + f;
            r0.x = f2bf(s[0]);
            r0.y = f2bf(s[(size_t)H2_]);
            r0.z = f2bf(s[(size_t)2 * H2_]);
            r0.w = f2bf(s[(size_t)3 * H2_]);
            r1.x = f2bf(s[(size_t)4 * H2_]);
            r1.y = f2bf(s[(size_t)5 * H2_]);
            r1.z = f2bf(s[(size_t)6 * H2_]);
            r1.w = f2bf(s[(size_t)7 * H2_]);
        }
        *reinterpret_cast<ushort4*>(dst + (size_t)o * 8) = r0;
        *reinterpret_cast<ushort4*>(dst + (size_t)o * 8 + 4) = r1;
    }
}

// ---------------- cvt2: w2 f32 -> fragment-packed bf16 B-panel ----------------
__global__ __launch_bounds__(256) void k_cvt2(const float* __restrict__ w2,
                                              unsigned short* __restrict__ w2p) {
    const int kt = blockIdx.x;   // 0..42
    const int nt = blockIdx.y;   // 0..7
    const int e  = blockIdx.z;
    const float* w2e = w2 + (size_t)e * H_ * D_;
    unsigned short* dst = w2p + (((size_t)((e * 8 + nt) * NKT2 + kt)) << 13);
#pragma unroll
    for (int i = 0; i < 4; ++i) {
        const int o = i * 256 + threadIdx.x;        // 0..1023
        const int l = o & 63, n16 = (o >> 6) & 7, k32 = o >> 9;
        const int d = nt * 128 + (n16 << 4) + (l & 15);
        const int f = kt * 64 + (k32 << 5) + ((l >> 4) << 3);
        const float* s = w2e + (size_t)f * D_ + d;
        ushort4 r0, r1;
        r0.x = (f + 0 < H_) ? f2bf(s[0]) : 0;
        r0.y = (f + 1 < H_) ? f2bf(s[(size_t)D_]) : 0;
        r0.z = (f + 2 < H_) ? f2bf(s[(size_t)2 * D_]) : 0;
        r0.w = (f + 3 < H_) ? f2bf(s[(size_t)3 * D_]) : 0;
        r1.x = (f + 4 < H_) ? f2bf(s[(size_t)4 * D_]) : 0;
        r1.y = (f + 5 < H_) ? f2bf(s[(size_t)5 * D_]) : 0;
        r1.z = (f + 6 < H_) ? f2bf(s[(size_t)6 * D_]) : 0;
        r1.w = (f + 7 < H_) ? f2bf(s[(size_t)7 * D_]) : 0;
        *reinterpret_cast<ushort4*>(dst + (size_t)o * 8) = r0;
        *reinterpret_cast<ushort4*>(dst + (size_t)o * 8 + 4) = r1;
    }
}

// ---------------- gating ----------------
__global__ __launch_bounds__(256) void k_gate(const float* __restrict__ x,
                                              const float* __restrict__ route,
                                              const float* __restrict__ gw,
                                              int* __restrict__ tokE,
                                              float* __restrict__ tokG,
                                              int* __restrict__ tokR) {
    const int wave = threadIdx.x >> 6, lane = threadIdx.x & 63;
    const int t = blockIdx.x * 4 + wave;
    float acc[E_];
#pragma unroll
    for (int e = 0; e < E_; ++e) acc[e] = 0.f;
    const float* xr = x + (size_t)t * D_;
    for (int d = lane; d < D_; d += 64) {
        float xv = xr[d];
        const float* g = gw + d * E_;
#pragma unroll
        for (int e = 0; e < E_; ++e) acc[e] = fmaf(xv, g[e], acc[e]);
    }
#pragma unroll
    for (int e = 0; e < E_; ++e) {
#pragma unroll
        for (int off = 32; off; off >>= 1) acc[e] += __shfl_xor(acc[e], off);
    }
    if (lane == 0) {
        float m = acc[0];
#pragma unroll
        for (int e = 1; e < E_; ++e) m = fmaxf(m, acc[e]);
        float p[E_]; float s = 0.f;
#pragma unroll
        for (int e = 0; e < E_; ++e) { p[e] = expf(acc[e] - m); s += p[e]; }
        int i0 = 0; float v0 = p[0];
#pragma unroll
        for (int e = 1; e < E_; ++e) if (p[e] > v0) { v0 = p[e]; i0 = e; }
        int i1 = (i0 == 0) ? 1 : 0; float v1 = p[i1];
#pragma unroll
        for (int e = 0; e < E_; ++e) if (e != i0 && p[e] > v1) { v1 = p[e]; i1 = e; }
        float p0 = v0 / s, p1 = v1 / s;
        float denom = fmaxf(p0 + p1, 1e-9f);
        float g0 = p0 / denom, g1 = p1 / denom;
        int r1 = route[NTOK + t] < (g1 / 0.2f);
        tokE[t] = i0; tokE[NTOK + t] = i1;
        tokG[t] = g0; tokG[NTOK + t] = g1;
        tokR[t] = r1;
    }
}

// ---------------- positions ----------------
__global__ __launch_bounds__(256) void k_pos(const int* __restrict__ tokE,
                                             const float* __restrict__ tokG,
                                             const int* __restrict__ tokR,
                                             int* __restrict__ sot,
                                             int* __restrict__ tos) {
    const int e = blockIdx.x & 7, b = blockIdx.x >> 3;
    const int t = threadIdx.x;
    __shared__ int sc[256];
    const int base_bt = b * N_ + t * 4;
    int m0[4], m1[4];
    int c0 = 0, c1 = 0;
#pragma unroll
    for (int i = 0; i < 4; ++i) {
        int bt = base_bt + i;
        m0[i] = (tokE[bt] == e) ? 1 : 0;
        m1[i] = ((tokE[NTOK + bt] == e) && tokR[bt]) ? 1 : 0;
        c0 += m0[i]; c1 += m1[i];
    }
    int packed = c0 | (c1 << 16);
    sc[t] = packed;
    __syncthreads();
    for (int off = 1; off < 256; off <<= 1) {
        int v = (t >= off) ? sc[t - off] : 0;
        __syncthreads();
        sc[t] += v;
        __syncthreads();
    }
    int incl = sc[t];
    int total = sc[255];
    int excl = incl - packed;
    int base0 = excl & 0xffff;
    int base1 = excl >> 16;
    int kept0 = min(total & 0xffff, CAP_);
#pragma unroll
    for (int i = 0; i < 4; ++i) {
        int bt = base_bt + i;
        if (m0[i]) {
            int pos = base0++;
            if (pos < CAP_ && tokG[bt] > 0.f) {
                int s = ((e * B_ + b) << 8) + pos;
                sot[bt] = s;
                tos[s] = bt;
            }
        }
        if (m1[i]) {
            int pos = (base1++) + kept0;
            if (pos < CAP_ && tokG[NTOK + bt] > 0.f) {
                int s = ((e * B_ + b) << 8) + pos;
                sot[NTOK + bt] = s;
                tos[s] = bt;
            }
        }
    }
}

// ---------------- dispatch: gather x rows -> fragment-packed bf16 xe ----------------
__global__ __launch_bounds__(256) void k_disp(const float* __restrict__ x,
                                              const int* __restrict__ tos,
                                              unsigned short* __restrict__ xeP) {
    const int t = threadIdx.x;
    const int s = blockIdx.x * 2 + (t >> 7);
    const int q = t & 127;                   // k-octet index
    const int bt = tos[s];
    const int kt = q >> 3, k32 = (q >> 2) & 1, kq = q & 3;
    const int lane = (kq << 4) | (s & 15);
    const int m16 = (s >> 4) & 15;
    const int sgrp = s >> 8;
    unsigned short* dst = xeP + (((size_t)(sgrp * NKT1 + kt)) << 14) + (k32 << 13) + (m16 << 9) + lane * 8;
    ushort4 r0 = {0, 0, 0, 0}, r1 = {0, 0, 0, 0};
    if (bt >= 0) {
        const float4 v0 = *reinterpret_cast<const float4*>(x + ((size_t)bt << 10) + q * 8);
        const float4 v1 = *reinterpret_cast<const float4*>(x + ((size_t)bt << 10) + q * 8 + 4);
        r0.x = f2bf(v0.x); r0.y = f2bf(v0.y); r0.z = f2bf(v0.z); r0.w = f2bf(v0.w);
        r1.x = f2bf(v1.x); r1.y = f2bf(v1.y); r1.z = f2bf(v1.z); r1.w = f2bf(v1.w);
    }
    *reinterpret_cast<ushort4*>(dst) = r0;
    *reinterpret_cast<ushort4*>(dst + 4) = r1;
}

// ---------------- GEMM1 + GEGLU: 256x(128x2) tile, 4-phase, dbuf, conflict-free ----------------
__global__ __launch_bounds__(512) void k_ffn1(const unsigned short* __restrict__ xeP,
                                              const unsigned short* __restrict__ w1p,
                                              const float* __restrict__ b1,
                                              const float* __restrict__ mbias,
                                              unsigned short* __restrict__ actP) {
    const int wg = blockIdx.x;               // 704 = 8 XCD * 88
    const int e = wg & 7;                    // expert per XCD
    const int rem = wg >> 3;                 // 0..87
    const int fg = rem >> 2;                 // 0..21
    const int rt = rem & 3;                  // 0..3
    const int sgrp = e * 4 + rt;

    __shared__ unsigned short Ab[2][16384];  // 32KB x2
    __shared__ unsigned short Bb[2][16384];  // 32KB x2

    const int tid = threadIdx.x, lane = tid & 63, w = tid >> 6;
    const int wm = w >> 2, wn = w & 3;
    const int lane8 = lane * 8;
    const int woff = w * 1024;
    const int am0 = wm * 8, bn0 = wn * 2;

    const unsigned short* abase = xeP + ((size_t)(sgrp * NKT1) << 14);
    const unsigned short* bbase = w1p + ((size_t)((e * NFG + fg) * NKT1) << 14);

    f32x4 acc[8][4];
#pragma unroll
    for (int i = 0; i < 8; ++i)
#pragma unroll
        for (int j = 0; j < 4; ++j) acc[i][j] = (f32x4)(0.f);

#define LDA1(ks, m16) (*reinterpret_cast<const short8*>(&Ab[cur][(((ks) << 4) + (m16)) * 512 + lane8]))
#define LDB1(ks, n16) (*reinterpret_cast<const short8*>(&Bb[cur][(((ks) << 4) + (n16)) * 512 + lane8]))

    // prologue: stage tile 0 -> buf 0 (A 32KB + B 32KB, 8 gll/thread)
    {
#pragma unroll
        for (int hq = 0; hq < 2; ++hq) {
            const int off = hq * 8192 + woff;
            GLL16(abase + off + lane8, (char*)&Ab[0][off]);
            GLL16(abase + off + 512 + lane8, (char*)&Ab[0][off + 512]);
            GLL16(bbase + off + lane8, (char*)&Bb[0][off]);
            GLL16(bbase + off + 512 + lane8, (char*)&Bb[0][off + 512]);
        }
    }

    for (int kt = 0; kt < NKT1; ++kt) {
        __syncthreads();                     // waits vmcnt(0)+lgkm, then barrier
        const int cur = kt & 1, nx = cur ^ 1;
        const bool pf = (kt + 1 < NKT1);
        const unsigned short* asn = abase + ((size_t)(kt + 1) << 14);
        const unsigned short* bsn = bbase + ((size_t)(kt + 1) << 14);
        short8 af[4], bf[4];

        // ---- phase 0: stage A-half0(next); B frags ks=0; A mi 0..3 ks=0
        if (pf) {
            const int off = woff;
            GLL16(asn + off + lane8, (char*)&Ab[nx][off]);
            GLL16(asn + off + 512 + lane8, (char*)&Ab[nx][off + 512]);
        }
        bf[0] = LDB1(0, bn0); bf[1] = LDB1(0, bn0 + 1);
        bf[2] = LDB1(0, bn0 + 8); bf[3] = LDB1(0, bn0 + 9);
        af[0] = LDA1(0, am0 + 0); af[1] = LDA1(0, am0 + 1);
        af[2] = LDA1(0, am0 + 2); af[3] = LDA1(0, am0 + 3);
        __builtin_amdgcn_s_setprio(1);
#pragma unroll
        for (int mi = 0; mi < 4; ++mi)
#pragma unroll
            for (int n = 0; n < 4; ++n)
                acc[mi][n] = __builtin_amdgcn_mfma_f32_16x16x32_bf16(af[mi], bf[n], acc[mi][n], 0, 0, 0);
        __builtin_amdgcn_s_setprio(0);

        // ---- phase 1: stage A-half1(next); A mi 4..7 ks=0
        if (pf) {
            const int off = 8192 + woff;
            GLL16(asn + off + lane8, (char*)&Ab[nx][off]);
            GLL16(asn + off + 512 + lane8, (char*)&Ab[nx][off + 512]);
        }
        af[0] = LDA1(0, am0 + 4); af[1] = LDA1(0, am0 + 5);
        af[2] = LDA1(0, am0 + 6); af[3] = LDA1(0, am0 + 7);
        __builtin_amdgcn_s_setprio(1);
#pragma unroll
        for (int mi = 0; mi < 4; ++mi)
#pragma unroll
            for (int n = 0; n < 4; ++n)
                acc[4 + mi][n] = __builtin_amdgcn_mfma_f32_16x16x32_bf16(af[mi], bf[n], acc[4 + mi][n], 0, 0, 0);
        __builtin_amdgcn_s_setprio(0);

        // ---- phase 2: stage B-half0(next); B frags ks=1; A mi 0..3 ks=1
        if (pf) {
            const int off = woff;
            GLL16(bsn + off + lane8, (char*)&Bb[nx][off]);
            GLL16(bsn + off + 512 + lane8, (char*)&Bb[nx][off + 512]);
        }
        bf[0] = LDB1(1, bn0); bf[1] = LDB1(1, bn0 + 1);
        bf[2] = LDB1(1, bn0 + 8); bf[3] = LDB1(1, bn0 + 9);
        af[0] = LDA1(1, am0 + 0); af[1] = LDA1(1, am0 + 1);
        af[2] = LDA1(1, am0 + 2); af[3] = LDA1(1, am0 + 3);
        __builtin_amdgcn_s_setprio(1);
#pragma unroll
        for (int mi = 0; mi < 4; ++mi)
#pragma unroll
            for (int n = 0; n < 4; ++n)
                acc[mi][n] = __builtin_amdgcn_mfma_f32_16x16x32_bf16(af[mi], bf[n], acc[mi][n], 0, 0, 0);
        __builtin_amdgcn_s_setprio(0);

        // ---- phase 3: stage B-half1(next); A mi 4..7 ks=1
        if (pf) {
            const int off = 8192 + woff;
            GLL16(bsn + off + lane8, (char*)&Bb[nx][off]);
            GLL16(bsn + off + 512 + lane8, (char*)&Bb[nx][off + 512]);
        }
        af[0] = LDA1(1, am0 + 4); af[1] = LDA1(1, am0 + 5);
        af[2] = LDA1(1, am0 + 6); af[3] = LDA1(1, am0 + 7);
        __builtin_amdgcn_s_setprio(1);
#pragma unroll
        for (int mi = 0; mi < 4; ++mi)
#pragma unroll
            for (int n = 0; n < 4; ++n)
                acc[4 + mi][n] = __builtin_amdgcn_mfma_f32_16x16x32_bf16(af[mi], bf[n], acc[4 + mi][n], 0, 0, 0);
        __builtin_amdgcn_s_setprio(0);
    }
#undef LDA1
#undef LDB1

    // epilogue: bias + exact GELU + mult_bias -> fragment-packed act
    const float* b1e = b1 + (size_t)e * H2_;
    const float* mbe = mbias + (size_t)e * H_;
    const int colL = lane & 15, rq4 = (lane >> 4) * 4;
#pragma unroll
    for (int mi = 0; mi < 8; ++mi) {
        const int Rl = wm * 128 + mi * 16 + rq4;
#pragma unroll
        for (int vi = 0; vi < 2; ++vi) {
            const int f = fg * 128 + wn * 32 + vi * 16 + colL;
            if (f >= NKT2 * 64) continue;    // beyond act storage (2752)
            const bool real = f < H_;
            const float bv = real ? b1e[f] : 0.f;
            const float bg = real ? b1e[H_ + f] : 0.f;
            const float mv = real ? mbe[f] : 0.f;
            const int ktf = f >> 6, k32f = (f >> 5) & 1;
            const int lhi = ((f >> 3) & 3) << 4;
            const int bb = f & 7;
            const size_t cbase = ((size_t)(sgrp * NKT2 + ktf) << 14) + (k32f << 13);
#pragma unroll
            for (int j = 0; j < 4; ++j) {
                const int R = Rl + j;
                float a = 0.f;
                if (real) {
                    const float val = acc[mi][vi][j] + bv;
                    const float gt  = acc[mi][2 + vi][j] + bg;
                    a = 0.5f * gt * (1.f + erff(gt * 0.70710678118654752f)) * val * mv;
                }
                actP[cbase + ((R >> 4) << 9) + (size_t)((lhi | (R & 15)) * 8 + bb)] = f2bf(a);
            }
        }
    }
}

// ---------------- GEMM2: 256x128 tile, 4-phase, dbuf, conflict-free ----------------
__global__ __launch_bounds__(512) void k_ffn2(const unsigned short* __restrict__ actP,
                                              const unsigned short* __restrict__ w2p,
                                              const float* __restrict__ b2,
                                              float* __restrict__ oute) {
    const int wg = blockIdx.x;               // 256 = 8 XCD * 32
    const int e = wg & 7;
    const int rem = wg >> 3;                 // 0..31
    const int nt = rem >> 2;                 // 0..7
    const int mt = rem & 3;                  // 0..3
    const int sgrp = e * 4 + mt;

    __shared__ unsigned short Ab[2][16384];  // 32KB x2
    __shared__ unsigned short Bb[2][8192];   // 16KB x2

    const int tid = threadIdx.x, lane = tid & 63, w = tid >> 6;
    const int wm = w >> 2, wn = w & 3;
    const int lane8 = lane * 8;
    const int woff = w * 1024;               // A staging
    const int woffb = w * 512;               // B staging
    const int am0 = wm * 8, bn0 = wn * 2;

    const unsigned short* abase = actP + ((size_t)(sgrp * NKT2) << 14);
    const unsigned short* bbase = w2p + ((size_t)((e * 8 + nt) * NKT2) << 13);

    f32x4 acc[8][2];
#pragma unroll
    for (int i = 0; i < 8; ++i)
#pragma unroll
        for (int j = 0; j < 2; ++j) acc[i][j] = (f32x4)(0.f);

#define LDA2(ks, m16) (*reinterpret_cast<const short8*>(&Ab[cur][(((ks) << 4) + (m16)) * 512 + lane8]))
#define LDB2(ks, n16) (*reinterpret_cast<const short8*>(&Bb[cur][((ks) * 8 + (n16)) * 512 + lane8]))

    // prologue: stage tile 0 -> buf 0 (A 32KB, B 16KB => 6 gll/thread)
    {
#pragma unroll
        for (int hq = 0; hq < 2; ++hq) {
            const int off = hq * 8192 + woff;
            GLL16(abase + off + lane8, (char*)&Ab[0][off]);
            GLL16(abase + off + 512 + lane8, (char*)&Ab[0][off + 512]);
            const int boff = hq * 4096 + woffb;
            GLL16(bbase + boff + lane8, (char*)&Bb[0][boff]);
        }
    }

    for (int kt = 0; kt < NKT2; ++kt) {
        __syncthreads();
        const int cur = kt & 1, nx = cur ^ 1;
        const bool pf = (kt + 1 < NKT2);
        const unsigned short* asn = abase + ((size_t)(kt + 1) << 14);
        const unsigned short* bsn = bbase + ((size_t)(kt + 1) << 13);
        short8 af[4], bf[2];

        // ---- phase 0: stage A-half0(next); B ks=0; A mi0..3 ks=0
        if (pf) {
            const int off = woff;
            GLL16(asn + off + lane8, (char*)&Ab[nx][off]);
            GLL16(asn + off + 512 + lane8, (char*)&Ab[nx][off + 512]);
        }
        bf[0] = LDB2(0, bn0); bf[1] = LDB2(0, bn0 + 1);
        af[0] = LDA2(0, am0 + 0); af[1] = LDA2(0, am0 + 1);
        af[2] = LDA2(0, am0 + 2); af[3] = LDA2(0, am0 + 3);
        __builtin_amdgcn_s_setprio(1);
#pragma unroll
        for (int mi = 0; mi < 4; ++mi)
#pragma unroll
            for (int n = 0; n < 2; ++n)
                acc[mi][n] = __builtin_amdgcn_mfma_f32_16x16x32_bf16(af[mi], bf[n], acc[mi][n], 0, 0, 0);
        __builtin_amdgcn_s_setprio(0);

        // ---- phase 1: stage A-half1(next); A mi4..7 ks=0
        if (pf) {
            const int off = 8192 + woff;
            GLL16(asn + off + lane8, (char*)&Ab[nx][off]);
            GLL16(asn + off + 512 + lane8, (char*)&Ab[nx][off + 512]);
        }
        af[0] = LDA2(0, am0 + 4); af[1] = LDA2(0, am0 + 5);
        af[2] = LDA2(0, am0 + 6); af[3] = LDA2(0, am0 + 7);
        __builtin_amdgcn_s_setprio(1);
#pragma unroll
        for (int mi = 0; mi < 4; ++mi)
#pragma unroll
            for (int n = 0; n < 2; ++n)
                acc[4 + mi][n] = __builtin_amdgcn_mfma_f32_16x16x32_bf16(af[mi], bf[n], acc[4 + mi][n], 0, 0, 0);
        __builtin_amdgcn_s_setprio(0);

        // ---- phase 2: stage B-half0(next); B ks=1; A mi0..3 ks=1
        if (pf) {
            const int boff = woffb;
            GLL16(bsn + boff + lane8, (char*)&Bb[nx][boff]);
        }
        bf[0] = LDB2(1, bn0); bf[1] = LDB2(1, bn0 + 1);
        af[0] = LDA2(1, am0 + 0); af[1] = LDA2(1, am0 + 1);
        af[2] = LDA2(1, am0 + 2); af[3] = LDA2(1, am0 + 3);
        __builtin_amdgcn_s_setprio(1);
#pragma unroll
        for (int mi = 0; mi < 4; ++mi)
#pragma unroll
            for (int n = 0; n < 2; ++n)
                acc[mi][n] = __builtin_amdgcn_mfma_f32_16x16x32_bf16(af[mi], bf[n], acc[mi][n], 0, 0, 0);
        __builtin_amdgcn_s_setprio(0);

        // ---- phase 3: stage B-half1(next); A mi4..7 ks=1
        if (pf) {
            const int boff = 4096 + woffb;
            GLL16(bsn + boff + lane8, (char*)&Bb[nx][boff]);
        }
        af[0] = LDA2(1, am0 + 4); af[1] = LDA2(1, am0 + 5);
        af[2] = LDA2(1, am0 + 6); af[3] = LDA2(1, am0 + 7);
        __builtin_amdgcn_s_setprio(1);
#pragma unroll
        for (int mi = 0; mi < 4; ++mi)
#pragma unroll
            for (int n = 0; n < 2; ++n)
                acc[4 + mi][n] = __builtin_amdgcn_mfma_f32_16x16x32_bf16(af[mi], bf[n], acc[4 + mi][n], 0, 0, 0);
        __builtin_amdgcn_s_setprio(0);
    }
#undef LDA2
#undef LDB2

    const float* b2e = b2 + (size_t)e * D_;
    const int colL = lane & 15, rq4 = (lane >> 4) * 4;
#pragma unroll
    for (int mi = 0; mi < 8; ++mi) {
#pragma unroll
        for (int vi = 0; vi < 2; ++vi) {
            const int d = nt * 128 + wn * 32 + vi * 16 + colL;
            const float bb2 = b2e[d];
#pragma unroll
            for (int j = 0; j < 4; ++j) {
                const int R = mt * 256 + wm * 128 + mi * 16 + rq4 + j;
                oute[((size_t)(e * 1024 + R) << 10) + d] = acc[mi][vi][j] + bb2;
            }
        }
    }
}

// ---------------- combine ----------------
__global__ __launch_bounds__(256) void k_comb(const float* __restrict__ oute,
                                              const int* __restrict__ sot,
                                              const float* __restrict__ tokG,
                                              float* __restrict__ out) {
    const int bt = blockIdx.x;
    const int t = threadIdx.x;
    const int s0 = sot[bt], s1 = sot[NTOK + bt];
    const float g0 = tokG[bt], g1 = tokG[NTOK + bt];
    float r0 = 0.f, r1 = 0.f, r2 = 0.f, r3 = 0.f;
    if (s0 >= 0) {
        const float4 v = *reinterpret_cast<const float4*>(oute + ((size_t)s0 << 10) + t * 4);
        r0 += g0 * v.x; r1 += g0 * v.y; r2 += g0 * v.z; r3 += g0 * v.w;
    }
    if (s1 >= 0) {
        const float4 v = *reinterpret_cast<const float4*>(oute + ((size_t)s1 << 10) + t * 4);
        r0 += g1 * v.x; r1 += g1 * v.y; r2 += g1 * v.z; r3 += g1 * v.w;
    }
    float4 o; o.x = r0; o.y = r1; o.z = r2; o.w = r3;
    *reinterpret_cast<float4*>(out + ((size_t)bt << 10) + t * 4) = o;
}

extern "C" void kernel_launch(void* const* d_in, const int* in_sizes, int n_in,
                              void* d_out, int out_size, void* d_ws, size_t ws_size,
                              hipStream_t stream) {
    const float* x     = (const float*)d_in[0];
    const float* route = (const float*)d_in[1];
    const float* gw    = (const float*)d_in[2];
    const float* w1    = (const float*)d_in[3];
    const float* b1    = (const float*)d_in[4];
    const float* mb    = (const float*)d_in[5];
    const float* w2    = (const float*)d_in[6];
    const float* b2    = (const float*)d_in[7];
    float* out = (float*)d_out;

    char* ws = (char*)d_ws;
    int*   tokE = (int*)(ws + 0);
    float* tokG = (float*)(ws + 32768);
    int*   tokR = (int*)(ws + 65536);
    int*   sot  = (int*)(ws + 81920);
    int*   tos  = (int*)(ws + 114688);
    // fragment-packed buffers
    unsigned short* xeP  = (unsigned short*)(ws + 147456);      // 16.78 MB, end 16,924,672
    unsigned short* actP = (unsigned short*)(ws + 16924672);    // 45.09 MB, end 62,013,440
    unsigned short* w1p  = (unsigned short*)(ws + 62013440);    // 92.27 MB, end 154,288,128 (dead after ffn1)
    unsigned short* w2p  = (unsigned short*)(ws + 62013440);    // 45.09 MB overlay (written after ffn1)
    float* oute = (float*)(ws + 107102208);                     // 33.55 MB overlay, end 140,656,640

    hipMemsetAsync(sot, 0xFF, 65536, stream);  // sot + tos -> -1

    k_cvt1<<<dim3(NFG, NKT1, 8), 256, 0, stream>>>(w1, w1p);
    k_gate<<<NTOK / 4, 256, 0, stream>>>(x, route, gw, tokE, tokG, tokR);
    k_pos<<<E_ * B_, 256, 0, stream>>>(tokE, tokG, tokR, sot, tos);
    k_disp<<<NSLOT / 2, 256, 0, stream>>>(x, tos, xeP);
    k_ffn1<<<704, 512, 0, stream>>>(xeP, w1p, b1, mb, actP);
    k_cvt2<<<dim3(NKT2, 8, 8), 256, 0, stream>>>(w2, w2p);      // after ffn1: w2p overlays w1p
    k_ffn2<<<256, 512, 0, stream>>>(actP, w2p, b2, oute);
    k_comb<<<NTOK, 256, 0, stream>>>(oute, sot, tokG, out);
}